// Round 1
// baseline (35.179 us; speedup 1.0000x reference)
//
#include <hip/hip_runtime.h>
#include <hip/hip_bf16.h>
#include <math.h>

// Problem constants (from reference setup_inputs)
constexpr int B_  = 192;
constexpr int NY  = 48;
constexpr int NT  = 48;
constexpr int C_  = 6625;

// Kernel 1: one block per batch element b.
// Phase 1 (all 256 threads): gather relu'd pred/I values for all (t,j) into LDS.
// Phase 2 (wave 0, lanes 0..47): affine-scan recurrence over t; lane j holds state j.
__global__ __launch_bounds__(256) void ep_forward_kernel(
    const float* __restrict__ pred,
    const float* __restrict__ R,
    const float* __restrict__ I,
    const int*   __restrict__ tgt,
    float* __restrict__ out_logs)
{
    __shared__ float sP[NT][NY];
    __shared__ float sI[NT][NY];
    __shared__ int   sT[NT];

    const int b   = blockIdx.x;
    const int tid = threadIdx.x;

    if (tid < NT) sT[tid] = tgt[b * NT + tid];
    __syncthreads();

    // ---- Phase 1: gather (2304 elements per array, 9 per thread per array) ----
    const float* predB = pred + (size_t)b * NY * C_;
    const float* IB    = I    + (size_t)b * NY * C_;
    #pragma unroll
    for (int k = 0; k < 9; ++k) {
        int e = tid + k * 256;           // e in [0, 2304)
        int t = e / NY;
        int j = e - t * NY;
        int c = sT[t];
        size_t off = (size_t)j * C_ + (size_t)c;
        sP[t][j] = fmaxf(predB[off], 0.0f);
        sI[t][j] = fmaxf(IB[off],    0.0f);
    }
    __syncthreads();

    // ---- Phase 2: recurrence (wave 0, lanes 0..47 only) ----
    if (tid >= NY) return;
    const int j = tid;

    const float* Rb = R + ((size_t)b * NY + j) * 3;
    float R0 = Rb[0];
    float R1 = Rb[1];
    float R2 = Rb[2];
    float Imult  = (j == NY - 1) ? 1.0f : R1;
    float R2prev = __shfl_up(R2, 1);     // R2[j-1]; lane 0 value is masked below

    // row0[j] = prod_{k=1..j} pD[b,0,k],  pD[b,0,k] = (tgt[0]==1) ? 1 : R2[k]
    {
        float d0 = (sT[0] == 1) ? 1.0f : R2;
        float v  = (j == 0) ? 1.0f : d0;
        #pragma unroll
        for (int s = 1; s < 64; s <<= 1) {
            float p = __shfl_up(v, s);
            if (j >= s) v *= p;
        }
        // row = v below
        float row = v;

        for (int t = 0; t < NT - 1; ++t) {
            float pg = sP[t][j];
            float ig = sI[t][j];
            float pC = R0 * pg;
            float pI = Imult * ig;

            // a[j] = row[j]*pI[j] + row[j-1]*pC[j-1]
            float u  = row * pC;
            float up = __shfl_up(u, 1);
            float a  = row * pI + ((j >= 1) ? up : 0.0f);

            // x_j = a_j + x_{j-1} * d_{j-1},  d = pD[b,t+1,*]
            bool is1 = (sT[t + 1] == 1);
            float m = (j == 0) ? 0.0f : (is1 ? 1.0f : R2prev);
            float c = a;
            // Hillis-Steele scan of affine maps f_j(x) = m_j x + c_j
            #pragma unroll
            for (int s = 1; s < 64; s <<= 1) {
                float cp = __shfl_up(c, s);
                float mp = __shfl_up(m, s);
                if (j >= s) {
                    c = fmaf(m, cp, c);  // uses OLD m
                    m = m * mp;
                }
            }
            row = c;
        }

        if (j == NY - 1) out_logs[b] = logf(row);
    }
}

// Kernel 2: deterministic reduction of 192 per-batch logs -> mean
__global__ __launch_bounds__(256) void ep_reduce_kernel(
    const float* __restrict__ logs, float* __restrict__ out)
{
    const int tid = threadIdx.x;
    float v = (tid < B_) ? logs[tid] : 0.0f;
    #pragma unroll
    for (int s = 1; s < 64; s <<= 1) v += __shfl_xor(v, s);
    __shared__ float sw[4];
    if ((tid & 63) == 0) sw[tid >> 6] = v;
    __syncthreads();
    if (tid == 0) out[0] = (sw[0] + sw[1] + sw[2] + sw[3]) * (1.0f / (float)B_);
}

extern "C" void kernel_launch(void* const* d_in, const int* in_sizes, int n_in,
                              void* d_out, int out_size, void* d_ws, size_t ws_size,
                              hipStream_t stream) {
    const float* pred = (const float*)d_in[0];
    const float* R    = (const float*)d_in[1];
    const float* I    = (const float*)d_in[2];
    const int*   tgt  = (const int*)d_in[3];
    float* out  = (float*)d_out;
    float* logs = (float*)d_ws;   // 192 floats of scratch

    ep_forward_kernel<<<B_, 256, 0, stream>>>(pred, R, I, tgt, logs);
    ep_reduce_kernel<<<1, 256, 0, stream>>>(logs, out);
}